// Round 10
// baseline (616.923 us; speedup 1.0000x reference)
//
#include <hip/hip_runtime.h>
#include <hip/hip_bf16.h>
#include <math.h>

#define BB 2
#define CC 256
#define NN 6272      // 8*28*28
#define NT32 196     // 32-query tiles per batch
#define NKB32 196    // 32-key tiles per batch
#define SCL 0.09016844005f   // log2(e)/sqrt(256)  (folded into Q at projection)

typedef __attribute__((ext_vector_type(8))) short s8v;   // 8 bf16 (4 VGPRs)
typedef __attribute__((ext_vector_type(4))) float f4v;   // MFMA acc / 16B vec
typedef __attribute__((ext_vector_type(4))) unsigned short us4v;  // 4 bf16
typedef __attribute__((ext_vector_type(2))) unsigned int u2v;     // 2x packed bf16

__device__ inline unsigned short f2bf(float f) {
  unsigned u = __builtin_bit_cast(unsigned, f);
  u += 0x7fffu + ((u >> 16) & 1u);     // RNE
  return (unsigned short)(u >> 16);
}

__device__ inline float bf2f(unsigned short h) {
  unsigned u = (unsigned)h << 16;
  return __builtin_bit_cast(float, u);
}

// packed f32x2 -> bf16x2 (RNE), single VALU op (T12 recipe, HW-verified)
__device__ inline unsigned cvtpk(float lo, float hi) {
  unsigned r;
  asm("v_cvt_pk_bf16_f32 %0, %1, %2" : "=v"(r) : "v"(lo), "v"(hi));
  return r;
}

// ---------------------------------------------------------------------------
// fp32 weights -> bf16 (once per launch)
// ---------------------------------------------------------------------------
__global__ __launch_bounds__(256) void wcvt_kernel(
    const float* __restrict__ wq, const float* __restrict__ wk,
    const float* __restrict__ wv, unsigned short* __restrict__ Wb)
{
  int i = (blockIdx.x * 256 + threadIdx.x) * 4;   // grid 192 -> i < 196608
  const float* src = (i < 65536) ? wq : (i < 131072 ? wk : wv);
  int off = i & 65535;
  float4 v = *(const float4*)(src + off);
  ushort4 o;
  o.x = f2bf(v.x); o.y = f2bf(v.y); o.z = f2bf(v.z); o.w = f2bf(v.w);
  *(ushort4*)(Wb + i) = o;
}

// ---------------------------------------------------------------------------
// MFMA projection
// p=0: Q*SCL -> [B][N][C]   p=1: K -> [B][N][C]   p=2: V -> [B][C][N]
// ---------------------------------------------------------------------------
__global__ __launch_bounds__(256) void proj_kernel(
    const float* __restrict__ x, const float* __restrict__ ctx,
    const unsigned short* __restrict__ Wb,
    const float* __restrict__ bq, const float* __restrict__ bk,
    const float* __restrict__ bv,
    unsigned short* __restrict__ Q, unsigned short* __restrict__ Kk,
    unsigned short* __restrict__ V)
{
  const int p = blockIdx.z, b = blockIdx.y;
  const int n0 = blockIdx.x * 32;
  const int tid = threadIdx.x;
  const float* in = (p == 0 ? x : ctx) + (size_t)b * CC * NN;
  const unsigned short* W = Wb + (size_t)p * 65536;
  const float* bias = (p == 0 ? bq : (p == 1 ? bk : bv));

  __shared__ __align__(16) unsigned short lds[32][264];   // [n][c]
  for (int it = tid; it < 2048; it += 256) {
    int c  = it >> 3;
    int n4 = (it & 7) << 2;
    float4 v = *(const float4*)(in + (size_t)c * NN + n0 + n4);
    lds[n4 + 0][c] = f2bf(v.x);
    lds[n4 + 1][c] = f2bf(v.y);
    lds[n4 + 2][c] = f2bf(v.z);
    lds[n4 + 3][c] = f2bf(v.w);
  }
  __syncthreads();

  const int lane = tid & 63, l15 = lane & 15, g = lane >> 4;
  const int obase = (tid >> 6) * 64;

  f4v acc[4][2];
#pragma unroll
  for (int mt = 0; mt < 4; ++mt) {
    float4 b4 = *(const float4*)(bias + obase + mt * 16 + g * 4);
    f4v bi = {b4.x, b4.y, b4.z, b4.w};
    acc[mt][0] = bi; acc[mt][1] = bi;
  }

#pragma unroll
  for (int ks = 0; ks < 8; ++ks) {
    s8v bf0 = *(const s8v*)(&lds[l15][ks * 32 + g * 8]);
    s8v bf1 = *(const s8v*)(&lds[16 + l15][ks * 32 + g * 8]);
#pragma unroll
    for (int mt = 0; mt < 4; ++mt) {
      s8v wa = *(const s8v*)(W + (size_t)(obase + mt * 16 + l15) * CC + ks * 32 + g * 8);
      acc[mt][0] = __builtin_amdgcn_mfma_f32_16x16x32_bf16(wa, bf0, acc[mt][0], 0, 0, 0);
      acc[mt][1] = __builtin_amdgcn_mfma_f32_16x16x32_bf16(wa, bf1, acc[mt][1], 0, 0, 0);
    }
  }

  if (p == 0) {
#pragma unroll
    for (int mt = 0; mt < 4; ++mt)
#pragma unroll
      for (int qq = 0; qq < 2; ++qq)
#pragma unroll
        for (int r = 0; r < 4; ++r)
          acc[mt][qq][r] *= SCL;
  }

  if (p < 2) {
    unsigned short* dst = (p == 0 ? Q : Kk) + (size_t)b * NN * CC;
#pragma unroll
    for (int mt = 0; mt < 4; ++mt)
#pragma unroll
      for (int qq = 0; qq < 2; ++qq) {
        u2v pk = {cvtpk(acc[mt][qq][0], acc[mt][qq][1]),
                  cvtpk(acc[mt][qq][2], acc[mt][qq][3])};
        *(u2v*)(dst + (size_t)(n0 + qq * 16 + l15) * CC + obase + mt * 16 + g * 4) = pk;
      }
  } else {
    unsigned short* dstb = V + (size_t)b * CC * NN;
#pragma unroll
    for (int mt = 0; mt < 4; ++mt)
#pragma unroll
      for (int qq = 0; qq < 2; ++qq)
#pragma unroll
        for (int r = 0; r < 4; ++r)
          dstb[(size_t)(obase + mt * 16 + g * 4 + r) * NN + n0 + qq * 16 + l15] =
              f2bf(acc[mt][qq][r]);
  }
}

// ---------------------------------------------------------------------------
// Flash attention (no-max exp2), wave-pair split. v8 = r6 body (verified,
// 111 us) with occupancy bought via LDS, not registers (r9 lesson: the
// ~112-reg live state spills below a ~170 cap -> 1.4 GB scratch traffic).
// V is SINGLE-buffered: the va_ preload consumes V_lds into registers
// before the block-wide pair s_barrier (lgkmcnt(0) guarantees all waves'
// preloads complete), so next-tile V staging issued AFTER that barrier is
// race-free; its DMA lands before the next __syncthreads vmcnt drain.
// K stays double-buffered (read throughout QK while next-K stages).
// LDS = K dbuf 32K + V 16K + P 5K = 54272 B -> 3 blocks/CU = 12 waves/CU
// (was 2 blocks/8 waves). launch_bounds(256,3): VGPR cap 170 >= 112 live.
// split=3 -> 588 blocks <= 768 resident slots = one clean round.
// ---------------------------------------------------------------------------
__global__ __launch_bounds__(256, 3) void attn_kernel(
    const unsigned short* __restrict__ Qg,
    const unsigned short* __restrict__ Kg,
    const unsigned short* __restrict__ Vg,
    unsigned short* __restrict__ Opart,  // [wid32*split+s][8192] bf16
    float* __restrict__ ml,              // [wid32*split+s][64] (h-split partials)
    int split, int kb_base, int kb_rem)
{
  const int s     = blockIdx.x % split;
  const int stile = blockIdx.x / split;   // 0..195
  const int b     = stile / 98;
  const int qsup  = stile % 98;
  const int tid   = threadIdx.x;
  const int w     = tid >> 6;             // 0..3
  const int pr    = w >> 1;               // pair 0..1
  const int h     = w & 1;                // half within pair
  const int lane  = tid & 63;
  const int l15 = lane & 15, g = lane >> 4;
  const int wid32 = b * NT32 + qsup * 2 + pr;
  const int q0    = (qsup * 2 + pr) * 32;

  const int start = s * kb_base + (s < kb_rem ? s : kb_rem);
  const int cnt   = kb_base + (s < kb_rem ? 1 : 0);

  const unsigned short* Qb = Qg + (size_t)b * NN * CC;
  const unsigned short* Kb = Kg + (size_t)b * NN * CC;
  const unsigned short* Vb = Vg + (size_t)b * CC * NN;

  __shared__ __align__(16) unsigned short K_lds[2][32 * 256];  // 2 x 16 KB
  __shared__ __align__(16) unsigned short V_lds[256 * 32];     // 16 KB (single)
  __shared__ __align__(16) unsigned short P_lds[2][32][40];    // per-pair P, 5 KB

  // ---- per-lane invariant staging offsets (shorts) -------------------
  // waves 0-1: K chunks 0..1023; waves 2-3: V chunks 1024..2047
  int offs[8];
#pragma unroll
  for (int i = 0; i < 8; ++i) {
    const int chunk = w * 512 + i * 64 + lane;       // 0..2047 (16B units)
    if (chunk < 1024) {                              // K part
      const int r = chunk >> 5, cc = chunk & 31;
      offs[i] = r * CC + ((cc ^ (r & 15)) << 3);
    } else {                                         // V part
      const int vc = chunk - 1024;
      const int ch = vc >> 2, c3 = vc & 3;
      offs[i] = ch * NN + ((c3 ^ ((ch >> 1) & 3)) << 3);
    }
  }

  // ---- Q B-fragments for 32 queries pinned (64 VGPRs) ----------------
  s8v qf[2][8];
#pragma unroll
  for (int qt = 0; qt < 2; ++qt)
#pragma unroll
    for (int ks = 0; ks < 8; ++ks)
      qf[qt][ks] = *(const s8v*)(Qb + (size_t)(q0 + qt * 16 + l15) * CC + ks * 32 + g * 8);

  f4v ot[2][8];                            // [qt][mt]: channels h*128 + mt*16
  const f4v fz = {0.f, 0.f, 0.f, 0.f};
#pragma unroll
  for (int qt = 0; qt < 2; ++qt)
#pragma unroll
    for (int mt = 0; mt < 8; ++mt) ot[qt][mt] = fz;

  float lsum[2] = {0.f, 0.f};

  // ---- staging: K (waves 0-1, double-buffered) / V (waves 2-3, single)
  auto stageK = [&](int buf, int kb32) {
    if (w < 2) {
#pragma unroll
      for (int i = 0; i < 8; ++i) {
        int chunk = w * 512 + i * 64 + lane;           // 0..1023
        const unsigned short* gp = Kb + (size_t)kb32 * 8192 + offs[i];
        __builtin_amdgcn_global_load_lds(
            (const __attribute__((address_space(1))) unsigned int*)gp,
            (__attribute__((address_space(3))) unsigned int*)(&K_lds[buf][chunk * 8]),
            16, 0, 0);
      }
    }
  };
  auto stageV = [&](int kb32) {
    if (w >= 2) {
#pragma unroll
      for (int i = 0; i < 8; ++i) {
        int chunk = w * 512 + i * 64 + lane;           // 1024..2047
        int vc = chunk - 1024;
        const unsigned short* gp = Vb + (size_t)kb32 * 32 + offs[i];
        __builtin_amdgcn_global_load_lds(
            (const __attribute__((address_space(1))) unsigned int*)gp,
            (__attribute__((address_space(3))) unsigned int*)(&V_lds[vc * 8]),
            16, 0, 0);
      }
    }
  };

  stageK(0, start);
  stageV(start);
  int cur = 0;

  for (int ib = 0; ib < cnt; ++ib) {
    __syncthreads();                       // vmcnt drained: K[cur] + V staged
    if (ib + 1 < cnt) stageK(cur ^ 1, start + ib + 1);  // next K (dbuf)

    const unsigned short* Kl = &K_lds[cur][0];

    // ---- S^T = K[h-half] @ Q^T (16 keys x 32 queries; Q pre-scaled) --
    f4v st[2];
    st[0] = fz; st[1] = fz;
    __builtin_amdgcn_s_setprio(1);
#pragma unroll
    for (int ks = 0; ks < 8; ++ks) {
      const int co = ((ks * 4 + g) ^ l15) << 3;        // swizzled 16B chunk
      s8v ka = *(const s8v*)(Kl + (h * 16 + l15) * 256 + co);
      st[0] = __builtin_amdgcn_mfma_f32_16x16x32_bf16(ka, qf[0][ks], st[0], 0, 0, 0);
      st[1] = __builtin_amdgcn_mfma_f32_16x16x32_bf16(ka, qf[1][ks], st[1], 0, 0, 0);
    }
    __builtin_amdgcn_s_setprio(0);

    // ---- PV V-fragment preload into regs (V_lds consumed HERE) -------
    const int vo = (g ^ ((l15 >> 1) & 3)) << 3;        // swizzled 16B chunk
    s8v va_[8];
#pragma unroll
    for (int mt = 0; mt < 8; ++mt)
      va_[mt] = *(const s8v*)(&V_lds[(h * 128 + mt * 16 + l15) * 32 + vo]);

    // ---- P = exp2(S), accumulate l, write pair-shared P slice --------
#pragma unroll
    for (int qt = 0; qt < 2; ++qt) {
      float p0 = __builtin_amdgcn_exp2f(st[qt][0]);
      float p1 = __builtin_amdgcn_exp2f(st[qt][1]);
      float p2 = __builtin_amdgcn_exp2f(st[qt][2]);
      float p3 = __builtin_amdgcn_exp2f(st[qt][3]);
      lsum[qt] += (p0 + p1) + (p2 + p3);
      u2v pk = {cvtpk(p0, p1), cvtpk(p2, p3)};
      *(u2v*)(&P_lds[pr][qt * 16 + l15][h * 16 + g * 4]) = pk;
    }

    // ---- block barrier: LDS-only wait, NO vmcnt drain ----------------
    // After this barrier every wave's va_ regs and P slice are complete.
    __builtin_amdgcn_sched_barrier(0);
    asm volatile("s_waitcnt lgkmcnt(0)" ::: "memory");
    __builtin_amdgcn_s_barrier();
    __builtin_amdgcn_sched_barrier(0);

    if (ib + 1 < cnt) stageV(start + ib + 1);  // safe: V_lds fully consumed

    // ---- O^T += V^T[h-half channels] @ P^T (all 32 keys) -------------
    s8v pb0 = *(const s8v*)(&P_lds[pr][l15][g * 8]);
    s8v pb1 = *(const s8v*)(&P_lds[pr][16 + l15][g * 8]);
    __builtin_amdgcn_s_setprio(1);
#pragma unroll
    for (int mt = 0; mt < 8; ++mt) {
      ot[0][mt] = __builtin_amdgcn_mfma_f32_16x16x32_bf16(va_[mt], pb0, ot[0][mt], 0, 0, 0);
      ot[1][mt] = __builtin_amdgcn_mfma_f32_16x16x32_bf16(va_[mt], pb1, ot[1][mt], 0, 0, 0);
    }
    __builtin_amdgcn_s_setprio(0);

    cur ^= 1;
  }

  // ---- reduce l across the 4 g-groups (per key-half partials) --------
#pragma unroll
  for (int qt = 0; qt < 2; ++qt) {
    lsum[qt] += __shfl_xor(lsum[qt], 16);
    lsum[qt] += __shfl_xor(lsum[qt], 32);
  }

  // ---- nontemporal bf16 fragment-native partial dump -----------------
  unsigned short* Ob = Opart + (size_t)(wid32 * split + s) * 8192;
#pragma unroll
  for (int qt = 0; qt < 2; ++qt)
#pragma unroll
    for (int mt = 0; mt < 8; ++mt) {
      u2v o2 = {cvtpk(ot[qt][mt][0], ot[qt][mt][1]),
                cvtpk(ot[qt][mt][2], ot[qt][mt][3])};
      __builtin_nontemporal_store(
          o2, (u2v*)(Ob + qt * 4096 + (h * 8 + mt) * 256 + lane * 4));
    }

  if (lane < 16) {
    ml[(size_t)(wid32 * split + s) * 64 + h * 32 + lane]      = lsum[0];
    ml[(size_t)(wid32 * split + s) * 64 + h * 32 + 16 + lane] = lsum[1];
  }
}

// ---------------------------------------------------------------------------
// Merge: block = one 32-query tile (32 n x 256 c).
// Phase 1: read Opart fragment-native (dense 8B/lane), sum over splits,
//          normalize by L summed over split x key-half, deposit fp32 into
//          lds_o[c][n] (pad 33).
// Phase 2: fully-coalesced out = lds_o + x (128B line segments).
// ---------------------------------------------------------------------------
__global__ __launch_bounds__(256) void merge_kernel(
    const unsigned short* __restrict__ Opart,
    const float* __restrict__ ml,
    const float* __restrict__ x,
    float* __restrict__ out,
    int split)
{
  const int wid32 = blockIdx.x;             // 0..391
  const int b  = wid32 / NT32;
  const int pi = wid32 % NT32;
  const int n0 = pi * 32;
  const int tid = threadIdx.x;
  const int w = tid >> 6;
  const int lane = tid & 63;
  const int l15 = lane & 15, g = lane >> 4;

  __shared__ float lds_o[256][33];          // 33.8 KB

#pragma unroll
  for (int t = 0; t < 2; ++t) {
    float L = 0.f;
#pragma unroll
    for (int s = 0; s < 8; ++s)
      if (s < split) {
        L += ml[(size_t)(wid32 * split + s) * 64 + t * 16 + l15];
        L += ml[(size_t)(wid32 * split + s) * 64 + 32 + t * 16 + l15];
      }
    const float invL = 1.f / L;

#pragma unroll
    for (int j = 0; j < 4; ++j) {
      int mt = j * 4 + w;
      float a0 = 0.f, a1 = 0.f, a2 = 0.f, a3 = 0.f;
#pragma unroll
      for (int s = 0; s < 8; ++s)
        if (s < split) {
          const us4v* Op4 = (const us4v*)(Opart +
              (size_t)(wid32 * split + s) * 8192 + t * 4096);
          us4v o4 = __builtin_nontemporal_load(Op4 + mt * 64 + lane);
          a0 += bf2f(o4.x); a1 += bf2f(o4.y);
          a2 += bf2f(o4.z); a3 += bf2f(o4.w);
        }
      int c = mt * 16 + g * 4;
      int nl = t * 16 + l15;
      lds_o[c + 0][nl] = a0 * invL;
      lds_o[c + 1][nl] = a1 * invL;
      lds_o[c + 2][nl] = a2 * invL;
      lds_o[c + 3][nl] = a3 * invL;
    }
  }
  __syncthreads();

  const size_t base = (size_t)b * CC * NN + n0;
  const int n = tid & 31;
  const int c0 = tid >> 5;                  // 0..7
#pragma unroll
  for (int cg = 0; cg < 32; ++cg) {
    int c = cg * 8 + c0;
    size_t idx = base + (size_t)c * NN + n;
    out[idx] = lds_o[c][n] + x[idx];
  }
}

extern "C" void kernel_launch(void* const* d_in, const int* in_sizes, int n_in,
                              void* d_out, int out_size, void* d_ws, size_t ws_size,
                              hipStream_t stream) {
  const float* x   = (const float*)d_in[0];
  const float* ctx = (const float*)d_in[1];
  const float* wq  = (const float*)d_in[2];
  const float* bq  = (const float*)d_in[3];
  const float* wk  = (const float*)d_in[4];
  const float* bk  = (const float*)d_in[5];
  const float* wv  = (const float*)d_in[6];
  const float* bv  = (const float*)d_in[7];
  float* out = (float*)d_out;

  const size_t sz = (size_t)BB * NN * CC;
  unsigned short* Wb = (unsigned short*)d_ws;        // 384 KB
  unsigned short* Q  = Wb + 3 * 65536;
  unsigned short* K  = Q + sz;
  unsigned short* V  = K + sz;
  const size_t fixedB = 3 * 65536 * 2 + 3 * sz * 2;  // 19.66 MB

  // split=3 -> 588 blocks <= 768 resident slots (3 blocks/CU x 256 CU)
  int split = 1;
  const int cands[3] = {3, 2, 1};
  for (int i = 0; i < 3; ++i) {
    size_t need = fixedB + (size_t)cands[i] * (BB * NT32) *
                  (8192 * sizeof(unsigned short) + 64 * sizeof(float));
    if (ws_size >= need) { split = cands[i]; break; }
  }
  unsigned short* Opart = (unsigned short*)((char*)d_ws + fixedB);
  float* ml = (float*)(Opart + (size_t)split * (BB * NT32) * 8192);
  const int kb_base = NKB32 / split, kb_rem = NKB32 % split;

  wcvt_kernel<<<dim3(192), dim3(256), 0, stream>>>(wq, wk, wv, Wb);
  proj_kernel<<<dim3(NN / 32, BB, 3), dim3(256), 0, stream>>>(
      x, ctx, Wb, bq, bk, bv, Q, K, V);
  attn_kernel<<<dim3(196 * split), dim3(256), 0, stream>>>(
      Q, K, V, Opart, ml, split, kb_base, kb_rem);
  merge_kernel<<<dim3(BB * NT32), dim3(256), 0, stream>>>(
      Opart, ml, x, out, split);
}

// Round 11
// 281.358 us; speedup vs baseline: 2.1927x; 2.1927x over previous
//
#include <hip/hip_runtime.h>
#include <hip/hip_bf16.h>
#include <math.h>

#define BB 2
#define CC 256
#define NN 6272      // 8*28*28
#define NT32 196     // 32-query tiles per batch
#define NKB32 196    // 32-key tiles per batch
#define SCL 0.09016844005f   // log2(e)/sqrt(256)  (folded into Q at projection)

typedef __attribute__((ext_vector_type(8))) short s8v;   // 8 bf16 (4 VGPRs)
typedef __attribute__((ext_vector_type(4))) float f4v;   // MFMA acc / 16B vec
typedef __attribute__((ext_vector_type(4))) unsigned short us4v;  // 4 bf16
typedef __attribute__((ext_vector_type(2))) unsigned int u2v;     // 2x packed bf16

__device__ inline unsigned short f2bf(float f) {
  unsigned u = __builtin_bit_cast(unsigned, f);
  u += 0x7fffu + ((u >> 16) & 1u);     // RNE
  return (unsigned short)(u >> 16);
}

__device__ inline float bf2f(unsigned short h) {
  unsigned u = (unsigned)h << 16;
  return __builtin_bit_cast(float, u);
}

// packed f32x2 -> bf16x2 (RNE), single VALU op (T12 recipe, HW-verified)
__device__ inline unsigned cvtpk(float lo, float hi) {
  unsigned r;
  asm("v_cvt_pk_bf16_f32 %0, %1, %2" : "=v"(r) : "v"(lo), "v"(hi));
  return r;
}

// ---------------------------------------------------------------------------
// fp32 weights -> bf16 (once per launch)
// ---------------------------------------------------------------------------
__global__ __launch_bounds__(256) void wcvt_kernel(
    const float* __restrict__ wq, const float* __restrict__ wk,
    const float* __restrict__ wv, unsigned short* __restrict__ Wb)
{
  int i = (blockIdx.x * 256 + threadIdx.x) * 4;   // grid 192 -> i < 196608
  const float* src = (i < 65536) ? wq : (i < 131072 ? wk : wv);
  int off = i & 65535;
  float4 v = *(const float4*)(src + off);
  ushort4 o;
  o.x = f2bf(v.x); o.y = f2bf(v.y); o.z = f2bf(v.z); o.w = f2bf(v.w);
  *(ushort4*)(Wb + i) = o;
}

// ---------------------------------------------------------------------------
// MFMA projection
// p=0: Q*SCL -> [B][N][C]   p=1: K -> [B][N][C]   p=2: V -> [B][C][N]
// ---------------------------------------------------------------------------
__global__ __launch_bounds__(256) void proj_kernel(
    const float* __restrict__ x, const float* __restrict__ ctx,
    const unsigned short* __restrict__ Wb,
    const float* __restrict__ bq, const float* __restrict__ bk,
    const float* __restrict__ bv,
    unsigned short* __restrict__ Q, unsigned short* __restrict__ Kk,
    unsigned short* __restrict__ V)
{
  const int p = blockIdx.z, b = blockIdx.y;
  const int n0 = blockIdx.x * 32;
  const int tid = threadIdx.x;
  const float* in = (p == 0 ? x : ctx) + (size_t)b * CC * NN;
  const unsigned short* W = Wb + (size_t)p * 65536;
  const float* bias = (p == 0 ? bq : (p == 1 ? bk : bv));

  __shared__ __align__(16) unsigned short lds[32][264];   // [n][c]
  for (int it = tid; it < 2048; it += 256) {
    int c  = it >> 3;
    int n4 = (it & 7) << 2;
    float4 v = *(const float4*)(in + (size_t)c * NN + n0 + n4);
    lds[n4 + 0][c] = f2bf(v.x);
    lds[n4 + 1][c] = f2bf(v.y);
    lds[n4 + 2][c] = f2bf(v.z);
    lds[n4 + 3][c] = f2bf(v.w);
  }
  __syncthreads();

  const int lane = tid & 63, l15 = lane & 15, g = lane >> 4;
  const int obase = (tid >> 6) * 64;

  f4v acc[4][2];
#pragma unroll
  for (int mt = 0; mt < 4; ++mt) {
    float4 b4 = *(const float4*)(bias + obase + mt * 16 + g * 4);
    f4v bi = {b4.x, b4.y, b4.z, b4.w};
    acc[mt][0] = bi; acc[mt][1] = bi;
  }

#pragma unroll
  for (int ks = 0; ks < 8; ++ks) {
    s8v bf0 = *(const s8v*)(&lds[l15][ks * 32 + g * 8]);
    s8v bf1 = *(const s8v*)(&lds[16 + l15][ks * 32 + g * 8]);
#pragma unroll
    for (int mt = 0; mt < 4; ++mt) {
      s8v wa = *(const s8v*)(W + (size_t)(obase + mt * 16 + l15) * CC + ks * 32 + g * 8);
      acc[mt][0] = __builtin_amdgcn_mfma_f32_16x16x32_bf16(wa, bf0, acc[mt][0], 0, 0, 0);
      acc[mt][1] = __builtin_amdgcn_mfma_f32_16x16x32_bf16(wa, bf1, acc[mt][1], 0, 0, 0);
    }
  }

  if (p == 0) {
#pragma unroll
    for (int mt = 0; mt < 4; ++mt)
#pragma unroll
      for (int qq = 0; qq < 2; ++qq)
#pragma unroll
        for (int r = 0; r < 4; ++r)
          acc[mt][qq][r] *= SCL;
  }

  if (p < 2) {
    unsigned short* dst = (p == 0 ? Q : Kk) + (size_t)b * NN * CC;
#pragma unroll
    for (int mt = 0; mt < 4; ++mt)
#pragma unroll
      for (int qq = 0; qq < 2; ++qq) {
        u2v pk = {cvtpk(acc[mt][qq][0], acc[mt][qq][1]),
                  cvtpk(acc[mt][qq][2], acc[mt][qq][3])};
        *(u2v*)(dst + (size_t)(n0 + qq * 16 + l15) * CC + obase + mt * 16 + g * 4) = pk;
      }
  } else {
    unsigned short* dstb = V + (size_t)b * CC * NN;
#pragma unroll
    for (int mt = 0; mt < 4; ++mt)
#pragma unroll
      for (int qq = 0; qq < 2; ++qq)
#pragma unroll
        for (int r = 0; r < 4; ++r)
          dstb[(size_t)(obase + mt * 16 + g * 4 + r) * NN + n0 + qq * 16 + l15] =
              f2bf(acc[mt][qq][r]);
  }
}

// ---------------------------------------------------------------------------
// Flash attention (no-max exp2), wave-pair split. v9 = r10 body byte-identical
// (passed; structure proven correct) with __launch_bounds__(256, 2).
// r10 lesson: the min-waves=3 arg made the backend target ~6 waves/SIMD and
// allocate 84 VGPRs for a ~112-reg live state -> ~16 MB scratch spill each
// way on the K-loop critical path -> 505 us. With (256,2) the allocator
// gives the natural ~112 regs (verified r6); occupancy comes from LDS:
// 54272 B/block -> 3 blocks/CU = 12 waves/CU (reg file admits 4 waves/SIMD
// at 112 regs, so LDS is the binding limit as intended).
// V single-buffered: va_ preload consumes V_lds into regs before the
// lgkmcnt(0)+s_barrier, so next-tile V staging after that barrier is
// race-free and drains at the next __syncthreads. K double-buffered.
// split=3 -> 588 blocks <= 768 resident slots = one clean round.
// ---------------------------------------------------------------------------
__global__ __launch_bounds__(256, 2) void attn_kernel(
    const unsigned short* __restrict__ Qg,
    const unsigned short* __restrict__ Kg,
    const unsigned short* __restrict__ Vg,
    unsigned short* __restrict__ Opart,  // [wid32*split+s][8192] bf16
    float* __restrict__ ml,              // [wid32*split+s][64] (h-split partials)
    int split, int kb_base, int kb_rem)
{
  const int s     = blockIdx.x % split;
  const int stile = blockIdx.x / split;   // 0..195
  const int b     = stile / 98;
  const int qsup  = stile % 98;
  const int tid   = threadIdx.x;
  const int w     = tid >> 6;             // 0..3
  const int pr    = w >> 1;               // pair 0..1
  const int h     = w & 1;                // half within pair
  const int lane  = tid & 63;
  const int l15 = lane & 15, g = lane >> 4;
  const int wid32 = b * NT32 + qsup * 2 + pr;
  const int q0    = (qsup * 2 + pr) * 32;

  const int start = s * kb_base + (s < kb_rem ? s : kb_rem);
  const int cnt   = kb_base + (s < kb_rem ? 1 : 0);

  const unsigned short* Qb = Qg + (size_t)b * NN * CC;
  const unsigned short* Kb = Kg + (size_t)b * NN * CC;
  const unsigned short* Vb = Vg + (size_t)b * CC * NN;

  __shared__ __align__(16) unsigned short K_lds[2][32 * 256];  // 2 x 16 KB
  __shared__ __align__(16) unsigned short V_lds[256 * 32];     // 16 KB (single)
  __shared__ __align__(16) unsigned short P_lds[2][32][40];    // per-pair P, 5 KB

  // ---- per-lane invariant staging offsets (shorts) -------------------
  // waves 0-1: K chunks 0..1023; waves 2-3: V chunks 1024..2047
  int offs[8];
#pragma unroll
  for (int i = 0; i < 8; ++i) {
    const int chunk = w * 512 + i * 64 + lane;       // 0..2047 (16B units)
    if (chunk < 1024) {                              // K part
      const int r = chunk >> 5, cc = chunk & 31;
      offs[i] = r * CC + ((cc ^ (r & 15)) << 3);
    } else {                                         // V part
      const int vc = chunk - 1024;
      const int ch = vc >> 2, c3 = vc & 3;
      offs[i] = ch * NN + ((c3 ^ ((ch >> 1) & 3)) << 3);
    }
  }

  // ---- Q B-fragments for 32 queries pinned (64 VGPRs) ----------------
  s8v qf[2][8];
#pragma unroll
  for (int qt = 0; qt < 2; ++qt)
#pragma unroll
    for (int ks = 0; ks < 8; ++ks)
      qf[qt][ks] = *(const s8v*)(Qb + (size_t)(q0 + qt * 16 + l15) * CC + ks * 32 + g * 8);

  f4v ot[2][8];                            // [qt][mt]: channels h*128 + mt*16
  const f4v fz = {0.f, 0.f, 0.f, 0.f};
#pragma unroll
  for (int qt = 0; qt < 2; ++qt)
#pragma unroll
    for (int mt = 0; mt < 8; ++mt) ot[qt][mt] = fz;

  float lsum[2] = {0.f, 0.f};

  // ---- staging: K (waves 0-1, double-buffered) / V (waves 2-3, single)
  auto stageK = [&](int buf, int kb32) {
    if (w < 2) {
#pragma unroll
      for (int i = 0; i < 8; ++i) {
        int chunk = w * 512 + i * 64 + lane;           // 0..1023
        const unsigned short* gp = Kb + (size_t)kb32 * 8192 + offs[i];
        __builtin_amdgcn_global_load_lds(
            (const __attribute__((address_space(1))) unsigned int*)gp,
            (__attribute__((address_space(3))) unsigned int*)(&K_lds[buf][chunk * 8]),
            16, 0, 0);
      }
    }
  };
  auto stageV = [&](int kb32) {
    if (w >= 2) {
#pragma unroll
      for (int i = 0; i < 8; ++i) {
        int chunk = w * 512 + i * 64 + lane;           // 1024..2047
        int vc = chunk - 1024;
        const unsigned short* gp = Vb + (size_t)kb32 * 32 + offs[i];
        __builtin_amdgcn_global_load_lds(
            (const __attribute__((address_space(1))) unsigned int*)gp,
            (__attribute__((address_space(3))) unsigned int*)(&V_lds[vc * 8]),
            16, 0, 0);
      }
    }
  };

  stageK(0, start);
  stageV(start);
  int cur = 0;

  for (int ib = 0; ib < cnt; ++ib) {
    __syncthreads();                       // vmcnt drained: K[cur] + V staged
    if (ib + 1 < cnt) stageK(cur ^ 1, start + ib + 1);  // next K (dbuf)

    const unsigned short* Kl = &K_lds[cur][0];

    // ---- S^T = K[h-half] @ Q^T (16 keys x 32 queries; Q pre-scaled) --
    f4v st[2];
    st[0] = fz; st[1] = fz;
    __builtin_amdgcn_s_setprio(1);
#pragma unroll
    for (int ks = 0; ks < 8; ++ks) {
      const int co = ((ks * 4 + g) ^ l15) << 3;        // swizzled 16B chunk
      s8v ka = *(const s8v*)(Kl + (h * 16 + l15) * 256 + co);
      st[0] = __builtin_amdgcn_mfma_f32_16x16x32_bf16(ka, qf[0][ks], st[0], 0, 0, 0);
      st[1] = __builtin_amdgcn_mfma_f32_16x16x32_bf16(ka, qf[1][ks], st[1], 0, 0, 0);
    }
    __builtin_amdgcn_s_setprio(0);

    // ---- PV V-fragment preload into regs (V_lds consumed HERE) -------
    const int vo = (g ^ ((l15 >> 1) & 3)) << 3;        // swizzled 16B chunk
    s8v va_[8];
#pragma unroll
    for (int mt = 0; mt < 8; ++mt)
      va_[mt] = *(const s8v*)(&V_lds[(h * 128 + mt * 16 + l15) * 32 + vo]);

    // ---- P = exp2(S), accumulate l, write pair-shared P slice --------
#pragma unroll
    for (int qt = 0; qt < 2; ++qt) {
      float p0 = __builtin_amdgcn_exp2f(st[qt][0]);
      float p1 = __builtin_amdgcn_exp2f(st[qt][1]);
      float p2 = __builtin_amdgcn_exp2f(st[qt][2]);
      float p3 = __builtin_amdgcn_exp2f(st[qt][3]);
      lsum[qt] += (p0 + p1) + (p2 + p3);
      u2v pk = {cvtpk(p0, p1), cvtpk(p2, p3)};
      *(u2v*)(&P_lds[pr][qt * 16 + l15][h * 16 + g * 4]) = pk;
    }

    // ---- block barrier: LDS-only wait, NO vmcnt drain ----------------
    // After this barrier every wave's va_ regs and P slice are complete.
    __builtin_amdgcn_sched_barrier(0);
    asm volatile("s_waitcnt lgkmcnt(0)" ::: "memory");
    __builtin_amdgcn_s_barrier();
    __builtin_amdgcn_sched_barrier(0);

    if (ib + 1 < cnt) stageV(start + ib + 1);  // safe: V_lds fully consumed

    // ---- O^T += V^T[h-half channels] @ P^T (all 32 keys) -------------
    s8v pb0 = *(const s8v*)(&P_lds[pr][l15][g * 8]);
    s8v pb1 = *(const s8v*)(&P_lds[pr][16 + l15][g * 8]);
    __builtin_amdgcn_s_setprio(1);
#pragma unroll
    for (int mt = 0; mt < 8; ++mt) {
      ot[0][mt] = __builtin_amdgcn_mfma_f32_16x16x32_bf16(va_[mt], pb0, ot[0][mt], 0, 0, 0);
      ot[1][mt] = __builtin_amdgcn_mfma_f32_16x16x32_bf16(va_[mt], pb1, ot[1][mt], 0, 0, 0);
    }
    __builtin_amdgcn_s_setprio(0);

    cur ^= 1;
  }

  // ---- reduce l across the 4 g-groups (per key-half partials) --------
#pragma unroll
  for (int qt = 0; qt < 2; ++qt) {
    lsum[qt] += __shfl_xor(lsum[qt], 16);
    lsum[qt] += __shfl_xor(lsum[qt], 32);
  }

  // ---- nontemporal bf16 fragment-native partial dump -----------------
  unsigned short* Ob = Opart + (size_t)(wid32 * split + s) * 8192;
#pragma unroll
  for (int qt = 0; qt < 2; ++qt)
#pragma unroll
    for (int mt = 0; mt < 8; ++mt) {
      u2v o2 = {cvtpk(ot[qt][mt][0], ot[qt][mt][1]),
                cvtpk(ot[qt][mt][2], ot[qt][mt][3])};
      __builtin_nontemporal_store(
          o2, (u2v*)(Ob + qt * 4096 + (h * 8 + mt) * 256 + lane * 4));
    }

  if (lane < 16) {
    ml[(size_t)(wid32 * split + s) * 64 + h * 32 + lane]      = lsum[0];
    ml[(size_t)(wid32 * split + s) * 64 + h * 32 + 16 + lane] = lsum[1];
  }
}

// ---------------------------------------------------------------------------
// Merge: block = one 32-query tile (32 n x 256 c).
// Phase 1: read Opart fragment-native (dense 8B/lane), sum over splits,
//          normalize by L summed over split x key-half, deposit fp32 into
//          lds_o[c][n] (pad 33).
// Phase 2: fully-coalesced out = lds_o + x (128B line segments).
// ---------------------------------------------------------------------------
__global__ __launch_bounds__(256) void merge_kernel(
    const unsigned short* __restrict__ Opart,
    const float* __restrict__ ml,
    const float* __restrict__ x,
    float* __restrict__ out,
    int split)
{
  const int wid32 = blockIdx.x;             // 0..391
  const int b  = wid32 / NT32;
  const int pi = wid32 % NT32;
  const int n0 = pi * 32;
  const int tid = threadIdx.x;
  const int w = tid >> 6;
  const int lane = tid & 63;
  const int l15 = lane & 15, g = lane >> 4;

  __shared__ float lds_o[256][33];          // 33.8 KB

#pragma unroll
  for (int t = 0; t < 2; ++t) {
    float L = 0.f;
#pragma unroll
    for (int s = 0; s < 8; ++s)
      if (s < split) {
        L += ml[(size_t)(wid32 * split + s) * 64 + t * 16 + l15];
        L += ml[(size_t)(wid32 * split + s) * 64 + 32 + t * 16 + l15];
      }
    const float invL = 1.f / L;

#pragma unroll
    for (int j = 0; j < 4; ++j) {
      int mt = j * 4 + w;
      float a0 = 0.f, a1 = 0.f, a2 = 0.f, a3 = 0.f;
#pragma unroll
      for (int s = 0; s < 8; ++s)
        if (s < split) {
          const us4v* Op4 = (const us4v*)(Opart +
              (size_t)(wid32 * split + s) * 8192 + t * 4096);
          us4v o4 = __builtin_nontemporal_load(Op4 + mt * 64 + lane);
          a0 += bf2f(o4.x); a1 += bf2f(o4.y);
          a2 += bf2f(o4.z); a3 += bf2f(o4.w);
        }
      int c = mt * 16 + g * 4;
      int nl = t * 16 + l15;
      lds_o[c + 0][nl] = a0 * invL;
      lds_o[c + 1][nl] = a1 * invL;
      lds_o[c + 2][nl] = a2 * invL;
      lds_o[c + 3][nl] = a3 * invL;
    }
  }
  __syncthreads();

  const size_t base = (size_t)b * CC * NN + n0;
  const int n = tid & 31;
  const int c0 = tid >> 5;                  // 0..7
#pragma unroll
  for (int cg = 0; cg < 32; ++cg) {
    int c = cg * 8 + c0;
    size_t idx = base + (size_t)c * NN + n;
    out[idx] = lds_o[c][n] + x[idx];
  }
}

extern "C" void kernel_launch(void* const* d_in, const int* in_sizes, int n_in,
                              void* d_out, int out_size, void* d_ws, size_t ws_size,
                              hipStream_t stream) {
  const float* x   = (const float*)d_in[0];
  const float* ctx = (const float*)d_in[1];
  const float* wq  = (const float*)d_in[2];
  const float* bq  = (const float*)d_in[3];
  const float* wk  = (const float*)d_in[4];
  const float* bk  = (const float*)d_in[5];
  const float* wv  = (const float*)d_in[6];
  const float* bv  = (const float*)d_in[7];
  float* out = (float*)d_out;

  const size_t sz = (size_t)BB * NN * CC;
  unsigned short* Wb = (unsigned short*)d_ws;        // 384 KB
  unsigned short* Q  = Wb + 3 * 65536;
  unsigned short* K  = Q + sz;
  unsigned short* V  = K + sz;
  const size_t fixedB = 3 * 65536 * 2 + 3 * sz * 2;  // 19.66 MB

  // split=3 -> 588 blocks <= 768 resident slots (3 blocks/CU x 256 CU)
  int split = 1;
  const int cands[3] = {3, 2, 1};
  for (int i = 0; i < 3; ++i) {
    size_t need = fixedB + (size_t)cands[i] * (BB * NT32) *
                  (8192 * sizeof(unsigned short) + 64 * sizeof(float));
    if (ws_size >= need) { split = cands[i]; break; }
  }
  unsigned short* Opart = (unsigned short*)((char*)d_ws + fixedB);
  float* ml = (float*)(Opart + (size_t)split * (BB * NT32) * 8192);
  const int kb_base = NKB32 / split, kb_rem = NKB32 % split;

  wcvt_kernel<<<dim3(192), dim3(256), 0, stream>>>(wq, wk, wv, Wb);
  proj_kernel<<<dim3(NN / 32, BB, 3), dim3(256), 0, stream>>>(
      x, ctx, Wb, bq, bk, bv, Q, K, V);
  attn_kernel<<<dim3(196 * split), dim3(256), 0, stream>>>(
      Q, K, V, Opart, ml, split, kb_base, kb_rem);
  merge_kernel<<<dim3(BB * NT32), dim3(256), 0, stream>>>(
      Opart, ml, x, out, split);
}

// Round 12
// 235.449 us; speedup vs baseline: 2.6202x; 1.1950x over previous
//
#include <hip/hip_runtime.h>
#include <hip/hip_bf16.h>
#include <math.h>

#define BB 2
#define CC 256
#define NN 6272      // 8*28*28
#define NT32 196     // 32-query tiles per batch
#define NKB32 196    // 32-key tiles per batch
#define SCL 0.09016844005f   // log2(e)/sqrt(256)  (folded into Q at projection)

typedef __attribute__((ext_vector_type(8))) short s8v;   // 8 bf16 (4 VGPRs)
typedef __attribute__((ext_vector_type(4))) float f4v;   // MFMA acc / 16B vec
typedef __attribute__((ext_vector_type(4))) unsigned short us4v;  // 4 bf16
typedef __attribute__((ext_vector_type(2))) unsigned int u2v;     // 2x packed bf16

__device__ inline unsigned short f2bf(float f) {
  unsigned u = __builtin_bit_cast(unsigned, f);
  u += 0x7fffu + ((u >> 16) & 1u);     // RNE
  return (unsigned short)(u >> 16);
}

__device__ inline float bf2f(unsigned short h) {
  unsigned u = (unsigned)h << 16;
  return __builtin_bit_cast(float, u);
}

// packed f32x2 -> bf16x2 (RNE), single VALU op (T12 recipe, HW-verified)
__device__ inline unsigned cvtpk(float lo, float hi) {
  unsigned r;
  asm("v_cvt_pk_bf16_f32 %0, %1, %2" : "=v"(r) : "v"(lo), "v"(hi));
  return r;
}

// ---------------------------------------------------------------------------
// fp32 weights -> bf16 (once per launch)
// ---------------------------------------------------------------------------
__global__ __launch_bounds__(256) void wcvt_kernel(
    const float* __restrict__ wq, const float* __restrict__ wk,
    const float* __restrict__ wv, unsigned short* __restrict__ Wb)
{
  int i = (blockIdx.x * 256 + threadIdx.x) * 4;   // grid 192 -> i < 196608
  const float* src = (i < 65536) ? wq : (i < 131072 ? wk : wv);
  int off = i & 65535;
  float4 v = *(const float4*)(src + off);
  ushort4 o;
  o.x = f2bf(v.x); o.y = f2bf(v.y); o.z = f2bf(v.z); o.w = f2bf(v.w);
  *(ushort4*)(Wb + i) = o;
}

// ---------------------------------------------------------------------------
// MFMA projection
// p=0: Q*SCL -> [B][N][C]   p=1: K -> [B][N][C]   p=2: V -> [B][C][N]
// ---------------------------------------------------------------------------
__global__ __launch_bounds__(256) void proj_kernel(
    const float* __restrict__ x, const float* __restrict__ ctx,
    const unsigned short* __restrict__ Wb,
    const float* __restrict__ bq, const float* __restrict__ bk,
    const float* __restrict__ bv,
    unsigned short* __restrict__ Q, unsigned short* __restrict__ Kk,
    unsigned short* __restrict__ V)
{
  const int p = blockIdx.z, b = blockIdx.y;
  const int n0 = blockIdx.x * 32;
  const int tid = threadIdx.x;
  const float* in = (p == 0 ? x : ctx) + (size_t)b * CC * NN;
  const unsigned short* W = Wb + (size_t)p * 65536;
  const float* bias = (p == 0 ? bq : (p == 1 ? bk : bv));

  __shared__ __align__(16) unsigned short lds[32][264];   // [n][c]
  for (int it = tid; it < 2048; it += 256) {
    int c  = it >> 3;
    int n4 = (it & 7) << 2;
    float4 v = *(const float4*)(in + (size_t)c * NN + n0 + n4);
    lds[n4 + 0][c] = f2bf(v.x);
    lds[n4 + 1][c] = f2bf(v.y);
    lds[n4 + 2][c] = f2bf(v.z);
    lds[n4 + 3][c] = f2bf(v.w);
  }
  __syncthreads();

  const int lane = tid & 63, l15 = lane & 15, g = lane >> 4;
  const int obase = (tid >> 6) * 64;

  f4v acc[4][2];
#pragma unroll
  for (int mt = 0; mt < 4; ++mt) {
    float4 b4 = *(const float4*)(bias + obase + mt * 16 + g * 4);
    f4v bi = {b4.x, b4.y, b4.z, b4.w};
    acc[mt][0] = bi; acc[mt][1] = bi;
  }

#pragma unroll
  for (int ks = 0; ks < 8; ++ks) {
    s8v bf0 = *(const s8v*)(&lds[l15][ks * 32 + g * 8]);
    s8v bf1 = *(const s8v*)(&lds[16 + l15][ks * 32 + g * 8]);
#pragma unroll
    for (int mt = 0; mt < 4; ++mt) {
      s8v wa = *(const s8v*)(W + (size_t)(obase + mt * 16 + l15) * CC + ks * 32 + g * 8);
      acc[mt][0] = __builtin_amdgcn_mfma_f32_16x16x32_bf16(wa, bf0, acc[mt][0], 0, 0, 0);
      acc[mt][1] = __builtin_amdgcn_mfma_f32_16x16x32_bf16(wa, bf1, acc[mt][1], 0, 0, 0);
    }
  }

  if (p == 0) {
#pragma unroll
    for (int mt = 0; mt < 4; ++mt)
#pragma unroll
      for (int qq = 0; qq < 2; ++qq)
#pragma unroll
        for (int r = 0; r < 4; ++r)
          acc[mt][qq][r] *= SCL;
  }

  if (p < 2) {
    unsigned short* dst = (p == 0 ? Q : Kk) + (size_t)b * NN * CC;
#pragma unroll
    for (int mt = 0; mt < 4; ++mt)
#pragma unroll
      for (int qq = 0; qq < 2; ++qq) {
        u2v pk = {cvtpk(acc[mt][qq][0], acc[mt][qq][1]),
                  cvtpk(acc[mt][qq][2], acc[mt][qq][3])};
        *(u2v*)(dst + (size_t)(n0 + qq * 16 + l15) * CC + obase + mt * 16 + g * 4) = pk;
      }
  } else {
    unsigned short* dstb = V + (size_t)b * CC * NN;
#pragma unroll
    for (int mt = 0; mt < 4; ++mt)
#pragma unroll
      for (int qq = 0; qq < 2; ++qq)
#pragma unroll
        for (int r = 0; r < 4; ++r)
          dstb[(size_t)(obase + mt * 16 + g * 4 + r) * NN + n0 + qq * 16 + l15] =
              f2bf(acc[mt][qq][r]);
  }
}

// ---------------------------------------------------------------------------
// Flash attention (no-max exp2), wave-pair split. LOCKED CHAMPION (r6,
// 235.84 us total / 111 us attn, verified). 256-thread blocks = 4 waves =
// 2 pairs; each pair owns 32 queries. Wave h of a pair: QK on keys
// h*16..+15 (8 K-frag b128 reads), P exchange via per-pair LDS + lgkmcnt-
// only s_barrier (staging prefetch survives it), PV on channels
// h*128..+127 with V-fragments PRELOADED into 32 VGPRs during the SM phase
// (covered by the same barrier). K and V both double-buffered via
// global_load_lds (16B) with per-lane invariant offsets (offs[8]).
// 2 blocks/CU (LDS 69.6 KB), ~112 VGPR at launch_bounds(256,2).
// Occupancy-raising variants all regressed and are rejected by measurement:
//   512-thr/(512,4): allocator capped 64 VGPR -> 1.4 GB spill (r9);
//   (256,3): allocator targeted 84 VGPR -> 16 MB spill (r10);
//   single-buffered V at (256,2): V-DMA window < HBM latency -> +56 us (r11).
// ---------------------------------------------------------------------------
__global__ __launch_bounds__(256, 2) void attn_kernel(
    const unsigned short* __restrict__ Qg,
    const unsigned short* __restrict__ Kg,
    const unsigned short* __restrict__ Vg,
    unsigned short* __restrict__ Opart,  // [wid32*split+s][8192] bf16
    float* __restrict__ ml,              // [wid32*split+s][64] (h-split partials)
    int split, int kb_base, int kb_rem)
{
  const int s     = blockIdx.x % split;
  const int stile = blockIdx.x / split;   // 0..195
  const int b     = stile / 98;
  const int qsup  = stile % 98;
  const int tid   = threadIdx.x;
  const int w     = tid >> 6;             // 0..3
  const int pr    = w >> 1;               // pair 0..1
  const int h     = w & 1;                // half within pair
  const int lane  = tid & 63;
  const int l15 = lane & 15, g = lane >> 4;
  const int wid32 = b * NT32 + qsup * 2 + pr;
  const int q0    = (qsup * 2 + pr) * 32;

  const int start = s * kb_base + (s < kb_rem ? s : kb_rem);
  const int cnt   = kb_base + (s < kb_rem ? 1 : 0);

  const unsigned short* Qb = Qg + (size_t)b * NN * CC;
  const unsigned short* Kb = Kg + (size_t)b * NN * CC;
  const unsigned short* Vb = Vg + (size_t)b * CC * NN;

  __shared__ __align__(16) unsigned short K_lds[2][32 * 256];  // 2 x 16 KB
  __shared__ __align__(16) unsigned short V_lds[2][256 * 32];  // 2 x 16 KB
  __shared__ __align__(16) unsigned short P_lds[2][32][40];    // per-pair P, 5 KB

  // ---- per-lane invariant staging offsets (shorts) -------------------
  int offs[8];
#pragma unroll
  for (int i = 0; i < 8; ++i) {
    const int chunk = w * 512 + i * 64 + lane;       // 0..2047 (16B units)
    if (chunk < 1024) {                              // K part
      const int r = chunk >> 5, cc = chunk & 31;
      offs[i] = r * CC + ((cc ^ (r & 15)) << 3);
    } else {                                         // V part
      const int vc = chunk - 1024;
      const int ch = vc >> 2, c3 = vc & 3;
      offs[i] = ch * NN + ((c3 ^ ((ch >> 1) & 3)) << 3);
    }
  }

  // ---- Q B-fragments for 32 queries pinned (64 VGPRs) ----------------
  s8v qf[2][8];
#pragma unroll
  for (int qt = 0; qt < 2; ++qt)
#pragma unroll
    for (int ks = 0; ks < 8; ++ks)
      qf[qt][ks] = *(const s8v*)(Qb + (size_t)(q0 + qt * 16 + l15) * CC + ks * 32 + g * 8);

  f4v ot[2][8];                            // [qt][mt]: channels h*128 + mt*16
  const f4v fz = {0.f, 0.f, 0.f, 0.f};
#pragma unroll
  for (int qt = 0; qt < 2; ++qt)
#pragma unroll
    for (int mt = 0; mt < 8; ++mt) ot[qt][mt] = fz;

  float lsum[2] = {0.f, 0.f};

  // ---- async stage of one 32-key tile (K waves 0-1, V waves 2-3) -----
  auto stage = [&](int buf, int kb32) {
#pragma unroll
    for (int i = 0; i < 8; ++i) {
      int chunk = w * 512 + i * 64 + lane;             // 0..2047 (16B units)
      if (chunk < 1024) {                              // K part
        const unsigned short* gp = Kb + (size_t)kb32 * 8192 + offs[i];
        __builtin_amdgcn_global_load_lds(
            (const __attribute__((address_space(1))) unsigned int*)gp,
            (__attribute__((address_space(3))) unsigned int*)(&K_lds[buf][chunk * 8]),
            16, 0, 0);
      } else {                                         // V part
        int vc = chunk - 1024;
        const unsigned short* gp = Vb + (size_t)kb32 * 32 + offs[i];
        __builtin_amdgcn_global_load_lds(
            (const __attribute__((address_space(1))) unsigned int*)gp,
            (__attribute__((address_space(3))) unsigned int*)(&V_lds[buf][vc * 8]),
            16, 0, 0);
      }
    }
  };

  stage(0, start);
  int cur = 0;

  for (int ib = 0; ib < cnt; ++ib) {
    __syncthreads();                       // buf[cur] staged; prev tile done
    if (ib + 1 < cnt) stage(cur ^ 1, start + ib + 1);   // prefetch next

    const unsigned short* Kl = &K_lds[cur][0];
    const unsigned short* Vl = &V_lds[cur][0];

    // ---- S^T = K[h-half] @ Q^T (16 keys x 32 queries; Q pre-scaled) --
    f4v st[2];
    st[0] = fz; st[1] = fz;
    __builtin_amdgcn_s_setprio(1);
#pragma unroll
    for (int ks = 0; ks < 8; ++ks) {
      const int co = ((ks * 4 + g) ^ l15) << 3;        // swizzled 16B chunk
      s8v ka = *(const s8v*)(Kl + (h * 16 + l15) * 256 + co);
      st[0] = __builtin_amdgcn_mfma_f32_16x16x32_bf16(ka, qf[0][ks], st[0], 0, 0, 0);
      st[1] = __builtin_amdgcn_mfma_f32_16x16x32_bf16(ka, qf[1][ks], st[1], 0, 0, 0);
    }
    __builtin_amdgcn_s_setprio(0);

    // ---- PV V-fragment preload (depends only on V_lds[cur], stable) --
    const int vo = (g ^ ((l15 >> 1) & 3)) << 3;        // swizzled 16B chunk
    s8v va_[8];
#pragma unroll
    for (int mt = 0; mt < 8; ++mt)
      va_[mt] = *(const s8v*)(Vl + (h * 128 + mt * 16 + l15) * 32 + vo);

    // ---- P = exp2(S), accumulate l, write pair-shared P slice --------
#pragma unroll
    for (int qt = 0; qt < 2; ++qt) {
      float p0 = __builtin_amdgcn_exp2f(st[qt][0]);
      float p1 = __builtin_amdgcn_exp2f(st[qt][1]);
      float p2 = __builtin_amdgcn_exp2f(st[qt][2]);
      float p3 = __builtin_amdgcn_exp2f(st[qt][3]);
      lsum[qt] += (p0 + p1) + (p2 + p3);
      u2v pk = {cvtpk(p0, p1), cvtpk(p2, p3)};
      *(u2v*)(&P_lds[pr][qt * 16 + l15][h * 16 + g * 4]) = pk;
    }

    // ---- pair barrier: LDS-only wait, NO vmcnt drain (keeps prefetch)
    __builtin_amdgcn_sched_barrier(0);
    asm volatile("s_waitcnt lgkmcnt(0)" ::: "memory");
    __builtin_amdgcn_s_barrier();
    __builtin_amdgcn_sched_barrier(0);

    // ---- O^T += V^T[h-half channels] @ P^T (all 32 keys) -------------
    s8v pb0 = *(const s8v*)(&P_lds[pr][l15][g * 8]);
    s8v pb1 = *(const s8v*)(&P_lds[pr][16 + l15][g * 8]);
    __builtin_amdgcn_s_setprio(1);
#pragma unroll
    for (int mt = 0; mt < 8; ++mt) {
      ot[0][mt] = __builtin_amdgcn_mfma_f32_16x16x32_bf16(va_[mt], pb0, ot[0][mt], 0, 0, 0);
      ot[1][mt] = __builtin_amdgcn_mfma_f32_16x16x32_bf16(va_[mt], pb1, ot[1][mt], 0, 0, 0);
    }
    __builtin_amdgcn_s_setprio(0);

    cur ^= 1;
  }

  // ---- reduce l across the 4 g-groups (per key-half partials) --------
#pragma unroll
  for (int qt = 0; qt < 2; ++qt) {
    lsum[qt] += __shfl_xor(lsum[qt], 16);
    lsum[qt] += __shfl_xor(lsum[qt], 32);
  }

  // ---- nontemporal bf16 fragment-native partial dump -----------------
  unsigned short* Ob = Opart + (size_t)(wid32 * split + s) * 8192;
#pragma unroll
  for (int qt = 0; qt < 2; ++qt)
#pragma unroll
    for (int mt = 0; mt < 8; ++mt) {
      u2v o2 = {cvtpk(ot[qt][mt][0], ot[qt][mt][1]),
                cvtpk(ot[qt][mt][2], ot[qt][mt][3])};
      __builtin_nontemporal_store(
          o2, (u2v*)(Ob + qt * 4096 + (h * 8 + mt) * 256 + lane * 4));
    }

  if (lane < 16) {
    ml[(size_t)(wid32 * split + s) * 64 + h * 32 + lane]      = lsum[0];
    ml[(size_t)(wid32 * split + s) * 64 + h * 32 + 16 + lane] = lsum[1];
  }
}

// ---------------------------------------------------------------------------
// Merge: block = one 32-query tile (32 n x 256 c).
// Phase 1: read Opart fragment-native (dense 8B/lane), sum over splits,
//          normalize by L summed over split x key-half, deposit fp32 into
//          lds_o[c][n] (pad 33).
// Phase 2: fully-coalesced out = lds_o + x (128B line segments).
// ---------------------------------------------------------------------------
__global__ __launch_bounds__(256) void merge_kernel(
    const unsigned short* __restrict__ Opart,
    const float* __restrict__ ml,
    const float* __restrict__ x,
    float* __restrict__ out,
    int split)
{
  const int wid32 = blockIdx.x;             // 0..391
  const int b  = wid32 / NT32;
  const int pi = wid32 % NT32;
  const int n0 = pi * 32;
  const int tid = threadIdx.x;
  const int w = tid >> 6;
  const int lane = tid & 63;
  const int l15 = lane & 15, g = lane >> 4;

  __shared__ float lds_o[256][33];          // 33.8 KB

#pragma unroll
  for (int t = 0; t < 2; ++t) {
    float L = 0.f;
#pragma unroll
    for (int s = 0; s < 8; ++s)
      if (s < split) {
        L += ml[(size_t)(wid32 * split + s) * 64 + t * 16 + l15];
        L += ml[(size_t)(wid32 * split + s) * 64 + 32 + t * 16 + l15];
      }
    const float invL = 1.f / L;

#pragma unroll
    for (int j = 0; j < 4; ++j) {
      int mt = j * 4 + w;
      float a0 = 0.f, a1 = 0.f, a2 = 0.f, a3 = 0.f;
#pragma unroll
      for (int s = 0; s < 8; ++s)
        if (s < split) {
          const us4v* Op4 = (const us4v*)(Opart +
              (size_t)(wid32 * split + s) * 8192 + t * 4096);
          us4v o4 = __builtin_nontemporal_load(Op4 + mt * 64 + lane);
          a0 += bf2f(o4.x); a1 += bf2f(o4.y);
          a2 += bf2f(o4.z); a3 += bf2f(o4.w);
        }
      int c = mt * 16 + g * 4;
      int nl = t * 16 + l15;
      lds_o[c + 0][nl] = a0 * invL;
      lds_o[c + 1][nl] = a1 * invL;
      lds_o[c + 2][nl] = a2 * invL;
      lds_o[c + 3][nl] = a3 * invL;
    }
  }
  __syncthreads();

  const size_t base = (size_t)b * CC * NN + n0;
  const int n = tid & 31;
  const int c0 = tid >> 5;                  // 0..7
#pragma unroll
  for (int cg = 0; cg < 32; ++cg) {
    int c = cg * 8 + c0;
    size_t idx = base + (size_t)c * NN + n;
    out[idx] = lds_o[c][n] + x[idx];
  }
}

extern "C" void kernel_launch(void* const* d_in, const int* in_sizes, int n_in,
                              void* d_out, int out_size, void* d_ws, size_t ws_size,
                              hipStream_t stream) {
  const float* x   = (const float*)d_in[0];
  const float* ctx = (const float*)d_in[1];
  const float* wq  = (const float*)d_in[2];
  const float* bq  = (const float*)d_in[3];
  const float* wk  = (const float*)d_in[4];
  const float* bk  = (const float*)d_in[5];
  const float* wv  = (const float*)d_in[6];
  const float* bv  = (const float*)d_in[7];
  float* out = (float*)d_out;

  const size_t sz = (size_t)BB * NN * CC;
  unsigned short* Wb = (unsigned short*)d_ws;        // 384 KB
  unsigned short* Q  = Wb + 3 * 65536;
  unsigned short* K  = Q + sz;
  unsigned short* V  = K + sz;
  const size_t fixedB = 3 * 65536 * 2 + 3 * sz * 2;  // 19.66 MB

  int split = 1;
  const int cands[3] = {5, 2, 1};
  for (int i = 0; i < 3; ++i) {
    size_t need = fixedB + (size_t)cands[i] * (BB * NT32) *
                  (8192 * sizeof(unsigned short) + 64 * sizeof(float));
    if (ws_size >= need) { split = cands[i]; break; }
  }
  unsigned short* Opart = (unsigned short*)((char*)d_ws + fixedB);
  float* ml = (float*)(Opart + (size_t)split * (BB * NT32) * 8192);
  const int kb_base = NKB32 / split, kb_rem = NKB32 % split;

  wcvt_kernel<<<dim3(192), dim3(256), 0, stream>>>(wq, wk, wv, Wb);
  proj_kernel<<<dim3(NN / 32, BB, 3), dim3(256), 0, stream>>>(
      x, ctx, Wb, bq, bk, bv, Q, K, V);
  attn_kernel<<<dim3(196 * split), dim3(256), 0, stream>>>(
      Q, K, V, Opart, ml, split, kb_base, kb_rem);
  merge_kernel<<<dim3(BB * NT32), dim3(256), 0, stream>>>(
      Opart, ml, x, out, split);
}